// Round 8
// baseline (434.416 us; speedup 1.0000x reference)
//
#include <hip/hip_runtime.h>

#define SEQ 1024
#define NT 512   // 8 waves; wave w owns gate-preact cols [16w,16w+16) for r,z,n

typedef _Float16 half8 __attribute__((ext_vector_type(8)));  // 4 VGPRs
typedef float f32x4 __attribute__((ext_vector_type(4)));     // MFMA 16x16 accum

// h buffer layout (halfwords): [buf][0..127]=h_hi, [buf][160..287]=h_lo.
// lo offset 160 hw = 80 words = bank shift 16 -> a wave's 8 distinct A-read
// addresses (hl in {0,1} x quad in {0..3}) cover all 32 banks exactly once.
#define LO_OFF 160
#define HBUF 320

// Gates use exp2 directly: W_r,W_z,biases pre-scaled by log2e; W_n,bhn,win,bin
// pre-scaled by 2*log2e (tanh(t) = (1-e)/(1+e), e = 2^(-2*log2e*t)).
#define K1 1.44269504f
#define K2 2.88539008f

#define EXP2F(v) __builtin_amdgcn_exp2f(v)   // v_exp_f32: 2^x

__global__ __launch_bounds__(NT, 2)
void gru_kernel(const float* __restrict__ x,     // [B, S, 1]
                const float* __restrict__ w_ih,  // [3H, 1]
                const float* __restrict__ w_hh,  // [3H, H]
                const float* __restrict__ b_ih,  // [3H]
                const float* __restrict__ b_hh,  // [3H]
                const float* __restrict__ w_fc,  // [1, H]
                const float* __restrict__ b_fc,  // [1]
                float* __restrict__ out)         // [B, 1]
{
  __shared__ float xs[SEQ];
  __shared__ __align__(16) _Float16 hs[2][HBUF];
  __shared__ float red[8];

  const int t = threadIdx.x;
  const int b = blockIdx.x;
  const int w = t >> 6;          // wave 0..7
  const int L = t & 63;          // lane
  const int n = L & 15;          // MFMA col (unit in tile) == A-row m
  const int quad = L >> 4;       // k-slice; C reg_i = row 4*quad+i
  const int u = 16 * w + n;      // hidden unit
  const int hl = n & 1;          // A-row parity: even rows = h_hi, odd = h_lo

  // stage x[b,:] (coalesced)
  const float* xrow = x + (size_t)b * SEQ;
  for (int i = t; i < SEQ; i += NT) xs[i] = xrow[i];
  if (t < HBUF) hs[0][t] = (_Float16)0.f;

  // B fragments (persistent, fp16, pre-scaled): B[k=quad*8+i][col=n]
  half8 Bw[3][4];
#pragma unroll
  for (int g = 0; g < 3; ++g) {
    const float scale = (g == 2) ? K2 : K1;
    const float* row = w_hh + (size_t)(g * 128 + u) * 128;
#pragma unroll
    for (int kt = 0; kt < 4; ++kt) {
      union { _Float16 s[8]; half8 v; } tmp;
#pragma unroll
      for (int i = 0; i < 8; ++i)
        tmp.s[i] = (_Float16)(row[kt * 32 + quad * 8 + i] * scale);
      Bw[g][kt] = tmp.v;
    }
  }
  const float bcr  = (b_ih[u] + b_hh[u]) * K1;
  const float bcz  = (b_ih[128 + u] + b_hh[128 + u]) * K1;
  const float bin2 = b_ih[256 + u] * K2;
  const float bhn2 = b_hh[256 + u] * K2;
  const float wir = w_ih[u] * K1, wiz = w_ih[128 + u] * K1, win2 = w_ih[256 + u] * K2;

  // per-lane A-read base (halfwords): parity-selected hi/lo bank group
  const int abase = hl * LO_OFF + quad * 8;

  float hprev = 0.f;   // h[u], replicated across quads (identical math)
  __syncthreads();

#define MF(A, B, C) C = __builtin_amdgcn_mfma_f32_16x16x32_f16(A, B, C, 0, 0, 0)

  // One step. A even rows = h_hi, odd = h_lo; C reg0 = row 4q (hi-dot),
  // reg1 = row 4q+1 (lo-dot): y = C[0]+C[1] in-lane. C[0] pre-loaded with the
  // input-side gi/bias term; C[2],C[3] hold garbage rows, never read.
#define STEP(RD, WR, XT)                                                       \
  {                                                                            \
    const float xt = (XT);                                                     \
    half8 A[4];                                                                \
    _Pragma("unroll")                                                          \
    for (int kt = 0; kt < 4; ++kt)                                             \
      A[kt] = *(const half8*)&hs[RD][abase + kt * 32];                         \
    const float gn = fmaf(xt, win2, bin2);                                     \
    f32x4 ar, az, an;                                                          \
    ar[0] = fmaf(xt, wir, bcr); ar[1] = 0.f;                                   \
    az[0] = fmaf(xt, wiz, bcz); az[1] = 0.f;                                   \
    an[0] = bhn2;               an[1] = 0.f;                                   \
    _Pragma("unroll")                                                          \
    for (int kt = 0; kt < 4; ++kt) MF(A[kt], Bw[0][kt], ar);                   \
    _Pragma("unroll")                                                          \
    for (int kt = 0; kt < 4; ++kt) MF(A[kt], Bw[1][kt], az);                   \
    _Pragma("unroll")                                                          \
    for (int kt = 0; kt < 4; ++kt) MF(A[kt], Bw[2][kt], an);                   \
    const float yr = ar[0] + ar[1];                                            \
    const float yz = az[0] + az[1];                                            \
    const float r = __builtin_amdgcn_rcpf(1.f + EXP2F(-yr));                   \
    const float z = __builtin_amdgcn_rcpf(1.f + EXP2F(-yz));                   \
    const float dn2 = an[0] + an[1];                                           \
    const float yn = fmaf(r, dn2, gn);                                         \
    const float e = EXP2F(-yn);                                                \
    const float nn = (1.f - e) * __builtin_amdgcn_rcpf(1.f + e);               \
    hprev = nn + z * (hprev - nn);                                             \
    const _Float16 hih = (_Float16)hprev;                                      \
    const _Float16 loh = (_Float16)(hprev - (float)hih);                       \
    if (quad == 0) { hs[WR][u] = hih; hs[WR][LO_OFF + u] = loh; }              \
    __syncthreads();                                                           \
  }

  for (int s = 0; s < SEQ; s += 2) {
    const float xt0 = xs[s];
    const float xt1 = xs[s + 1];
    STEP(0, 1, xt0);
    STEP(1, 0, xt1);
  }
#undef STEP
#undef MF

  // epilogue: out[b] = relu(h_T) . w_fc + b_fc
  float v = (quad == 0) ? fmaxf(hprev, 0.f) * w_fc[u] : 0.f;
#pragma unroll
  for (int off = 1; off < 64; off <<= 1) v += __shfl_xor(v, off);
  if (L == 0) red[w] = v;
  __syncthreads();
  if (t == 0) {
    float sum = 0.f;
#pragma unroll
    for (int k = 0; k < 8; ++k) sum += red[k];
    out[b] = sum + b_fc[0];
  }
}

extern "C" void kernel_launch(void* const* d_in, const int* in_sizes, int n_in,
                              void* d_out, int out_size, void* d_ws, size_t ws_size,
                              hipStream_t stream) {
  const float* x    = (const float*)d_in[0];
  const float* w_ih = (const float*)d_in[1];
  const float* w_hh = (const float*)d_in[2];
  const float* b_ih = (const float*)d_in[3];
  const float* b_hh = (const float*)d_in[4];
  const float* w_fc = (const float*)d_in[5];
  const float* b_fc = (const float*)d_in[6];
  gru_kernel<<<256, NT, 0, stream>>>(x, w_ih, w_hh, b_ih, b_hh, w_fc, b_fc,
                                     (float*)d_out);
}